// Round 15
// baseline (294.326 us; speedup 1.0000x reference)
//
#include <hip/hip_runtime.h>
#include <hip/hip_bf16.h>

#define HID 1024
#define NH 16
#define HEAD 64
#define WIN 256
#define SEQ 4096
#define BATCH 4
#define NROWS (BATCH * SEQ)   // 16384
#define LN_EPS 1e-5f

typedef unsigned short u16;
typedef __bf16 bf16x8 __attribute__((ext_vector_type(8)));
typedef float f32x4 __attribute__((ext_vector_type(4)));

static __device__ inline float bfu(u16 u) {
    union { unsigned int i; float f; } x;
    x.i = ((unsigned int)u) << 16;
    return x.f;
}

static __device__ inline u16 f2bf(float f) {
    union { float f; unsigned int i; } x;
    x.f = f;
    unsigned int lsb = (x.i >> 16) & 1u;
    x.i += 0x7fffu + lsb;   // round-to-nearest-even
    return (u16)(x.i >> 16);
}

// ---------------------------------------------------------------- fused LN1 + weight convert
__global__ __launch_bounds__(256) void ln1_conv(
    const float* __restrict__ x, const float* __restrict__ g,
    const float* __restrict__ b, u16* __restrict__ out,
    const float* __restrict__ wq, const float* __restrict__ wk,
    const float* __restrict__ wv, const float* __restrict__ wp,
    u16* __restrict__ wo)
{
    __shared__ float red[8];
    int t = threadIdx.x;
    if (blockIdx.x >= NROWS) {
        int i = (blockIdx.x - NROWS) * 256 + t;
        const int n = 1024 * 1024;
        wo[i]         = f2bf(wq[i]);
        wo[n + i]     = f2bf(wk[i]);
        wo[2 * n + i] = f2bf(wv[i]);
        wo[3 * n + i] = f2bf(wp[i]);
        return;
    }
    int row = blockIdx.x;
    float4 v = ((const float4*)(x + (size_t)row * HID))[t];
    float s  = v.x + v.y + v.z + v.w;
    float ss = v.x * v.x + v.y * v.y + v.z * v.z + v.w * v.w;
    #pragma unroll
    for (int off = 32; off; off >>= 1) { s += __shfl_down(s, off); ss += __shfl_down(ss, off); }
    int wave = t >> 6, lane = t & 63;
    if (lane == 0) { red[wave] = s; red[4 + wave] = ss; }
    __syncthreads();
    float S  = red[0] + red[1] + red[2] + red[3];
    float SS = red[4] + red[5] + red[6] + red[7];
    float mean = S * (1.f / HID);
    float var  = SS * (1.f / HID) - mean * mean;
    float inv  = rsqrtf(var + LN_EPS);
    float4 gv = ((const float4*)g)[t];
    float4 bv = ((const float4*)b)[t];
    ushort4 o;
    o.x = f2bf((v.x - mean) * inv * gv.x + bv.x);
    o.y = f2bf((v.y - mean) * inv * gv.y + bv.y);
    o.z = f2bf((v.z - mean) * inv * gv.z + bv.z);
    o.w = f2bf((v.w - mean) * inv * gv.w + bv.w);
    ((ushort4*)(out + (size_t)row * HID))[t] = o;
}

// ---------------------------------------------------------------- 256x128 BK=32 triple-buffered GEMM
// K=1024 (nk=32). Wave grid 4M x 2N, per-wave 64x64 (acc 64 VGPR).
// LDS 3x24KB = 72KB -> 2 blocks/CU. Swizzle f(r)=(r>>1)&3 (0-conflict).
// Round-15: bn-FAST XCD decode (A-tile 512KB stays L2-hot across the bn
// sweep -> A fetched once per bm; B is chip-shared, L3 absorbs) + fused
// attn1-logits epilogue for bn<8 blocks (wave wc owns head bn*2+wc).
#define GLDS(gp, lp) __builtin_amdgcn_global_load_lds( \
    (const __attribute__((address_space(1))) void*)(gp), \
    (__attribute__((address_space(3))) void*)(lp), 16, 0, 0)

__global__ __launch_bounds__(512, 4) void gemm_bk32(
    const u16* __restrict__ A, const u16* __restrict__ W,
    u16* __restrict__ C, int ldc, int nbn,
    const float* __restrict__ qa,     // if non-null: fused logits for bn<8 tiles
    const float* __restrict__ mask,
    float* __restrict__ awout)
{
    // per buf (u16 units): A-unit0 [0,4096), A-unit1 [4096,8192), B [8192,12288)
    // A unit0 holds rows 0-63 & 128-191; unit1 rows 64-127 & 192-255.
    __shared__ __align__(16) u16 lds[3][12288];   // 72 KB

    const int tid = threadIdx.x;
    const int wave = tid >> 6, lane = tid & 63;
    const int wr = wave >> 1, wc = wave & 1;           // 4M x 2N
    const int li = lane & 15;
    const int kg = lane >> 4;                          // K-group 0..3
    const int swz = (kg * 8) ^ (((li >> 1) & 3) << 3); // swizzled elem-in-row

    // bn-fast XCD decode: xcd = bid&7 owns bm stripe [xcd*8, xcd*8+8);
    // within the stripe, bn varies fastest so the A-tile stays L2-hot.
    const int local = blockIdx.x >> 3;
    const int bn = local % nbn;
    const int bm = (blockIdx.x & 7) * 8 + local / nbn;

    // staging: thread covers 16B of row rp (0..127) in each 8KB unit;
    // source col pre-swizzled with the SAME f(r)=(r>>1)&3 involution.
    const int rp = tid >> 2;
    const int colE = (((tid & 3) * 16) ^ (((rp >> 1) & 3) << 4)) >> 1;  // elem col 0..31
    const int rowA0 = rp + (rp >= 64 ? 64 : 0);   // unit0: rows 0-63 & 128-191
    const u16* gA0 = A + (size_t)(bm * 256 + rowA0) * 1024 + colE;
    const u16* gA1 = gA0 + (size_t)64 * 1024;     // unit1: rows 64-127 & 192-255
    const u16* gB  = W + (size_t)(bn * 128 + rp) * 1024 + colE;

    // per-wave A source: unit (wr&1), base row (wr>>1)*64
    const int aUnit = (wr & 1) * 4096;
    const int aRow0 = (wr >> 1) * 64;

    // prologue: stage tiles 0,1 into bufs 0,1; drain tile 0.
    #pragma unroll
    for (int t = 0; t < 2; ++t) {
        u16* d = &lds[t][0];
        GLDS(gA0 + t * 32, d + tid * 8);
        GLDS(gA1 + t * 32, d + 4096 + tid * 8);
        GLDS(gB  + t * 32, d + 8192 + tid * 8);
    }
    asm volatile("s_waitcnt vmcnt(3)" ::: "memory");
    __builtin_amdgcn_sched_barrier(0);
    __builtin_amdgcn_s_barrier();
    __builtin_amdgcn_sched_barrier(0);

    f32x4 acc[4][4];
    #pragma unroll
    for (int m = 0; m < 4; ++m)
        #pragma unroll
        for (int n = 0; n < 4; ++n) {
            f32x4 z = {0.f, 0.f, 0.f, 0.f};
            acc[m][n] = z;
        }

    const u16* rb = &lds[0][0];
    const u16* rn = &lds[1][0];
    u16* wb = &lds[2][0];

    for (int kt = 0; kt < 32; ++kt) {
        // reads at top (tile kt's buf was drained at iter kt-1's wait)
        bf16x8 bF[4], aF01[2];
        #pragma unroll
        for (int n = 0; n < 4; ++n)
            bF[n] = *(const bf16x8*)&rb[8192 + (wc * 64 + n * 16 + li) * 32 + swz];
        #pragma unroll
        for (int i = 0; i < 2; ++i)
            aF01[i] = *(const bf16x8*)&rb[aUnit + (aRow0 + i * 16 + li) * 32 + swz];

        // stage tile kt+2 into wb (last read as rb at iter kt-1)
        if (kt < 30) {
            const int ko = (kt + 2) * 32;
            GLDS(gA0 + ko, wb + tid * 8);
            GLDS(gA1 + ko, wb + 4096 + tid * 8);
            GLDS(gB  + ko, wb + 8192 + tid * 8);
        }
        // wait: drain tile kt+1's 3 units (staged at iter kt-1, ~1 K-tile old)
        if (kt < 31) {
            if (kt < 30) asm volatile("s_waitcnt vmcnt(3)" ::: "memory");
            else         asm volatile("s_waitcnt vmcnt(0)" ::: "memory");
        }
        __builtin_amdgcn_sched_barrier(0);
        __builtin_amdgcn_s_barrier();
        __builtin_amdgcn_sched_barrier(0);

        __builtin_amdgcn_s_setprio(1);
        #pragma unroll
        for (int i = 0; i < 2; ++i)
            #pragma unroll
            for (int n = 0; n < 4; ++n)
                acc[i][n] = __builtin_amdgcn_mfma_f32_16x16x32_bf16(
                    aF01[i], bF[n], acc[i][n], 0, 0, 0);
        bf16x8 aF23[2];
        #pragma unroll
        for (int i = 0; i < 2; ++i)
            aF23[i] = *(const bf16x8*)&rb[aUnit + (aRow0 + (i + 2) * 16 + li) * 32 + swz];
        #pragma unroll
        for (int i = 0; i < 2; ++i)
            #pragma unroll
            for (int n = 0; n < 4; ++n)
                acc[2 + i][n] = __builtin_amdgcn_mfma_f32_16x16x32_bf16(
                    aF23[i], bF[n], acc[2 + i][n], 0, 0, 0);
        __builtin_amdgcn_s_setprio(0);
        __builtin_amdgcn_sched_barrier(0);
        __builtin_amdgcn_s_barrier();
        __builtin_amdgcn_sched_barrier(0);

        const u16* tmp = rb; rb = rn; rn = wb; wb = (u16*)tmp;
    }

    // fused attn1 logits: q cols are 0..1023 -> bn<8; wave wc owns head bn*2+wc.
    // A given output row lives in the 16-lane kg-group matching its kg*4+r.
    if (awout != nullptr && bn < 8) {
        float qav[4];
        #pragma unroll
        for (int n = 0; n < 4; ++n)
            qav[n] = qa[bn * 128 + wc * 64 + n * 16 + li];
        #pragma unroll
        for (int mf = 0; mf < 4; ++mf) {
            #pragma unroll
            for (int r = 0; r < 4; ++r) {
                float d = acc[mf][0][r] * qav[0] + acc[mf][1][r] * qav[1]
                        + acc[mf][2][r] * qav[2] + acc[mf][3][r] * qav[3];
                d += __shfl_xor(d, 1);
                d += __shfl_xor(d, 2);
                d += __shfl_xor(d, 4);
                d += __shfl_xor(d, 8);
                if (li == 0) {
                    int row = bm * 256 + wr * 64 + mf * 16 + kg * 4 + r;
                    float ma = (1.0f - mask[row]) * -10000.0f;
                    awout[(((size_t)(row >> 12)) * NH + bn * 2 + wc) * SEQ + (row & (SEQ - 1))] =
                        expf(d * 0.125f + ma);
                }
            }
        }
    }

    #pragma unroll
    for (int mf = 0; mf < 4; ++mf) {
        int row0 = bm * 256 + wr * 64 + mf * 16 + kg * 4;
        #pragma unroll
        for (int n = 0; n < 4; ++n) {
            int col = bn * 128 + wc * 64 + n * 16 + li;
            #pragma unroll
            for (int r = 0; r < 4; ++r)
                C[(size_t)(row0 + r) * ldc + col] = f2bf(acc[mf][n][r]);
        }
    }
}

// ---------------------------------------------------------------- windowed scan attention, 2 heads/block
// fused==0: out_bf <- windowed avg (bf16). fused==1: outF <- res + win*v (write-only).
__global__ __launch_bounds__(512) void attn_win2(
    const u16* __restrict__ x, int xstride,
    const float* __restrict__ aw_g,
    u16* __restrict__ out_bf,
    const u16* __restrict__ resv,   // qkv base: res in cols 0..1023, v in cols 2048..3071
    float* __restrict__ outF,
    int fused)
{
    int c = blockIdx.x, h2 = blockIdx.y, b = blockIdx.z;
    __shared__ float awl[2][2][WIN];     // [head][chunk][j]
    __shared__ float2 sts[2][8][64];     // [chunk][wave][lane]
    __shared__ float stz[2][8][2];       // [chunk][wave][head]

    int t = threadIdx.x, wave = t >> 6, lane = t & 63;
    int hh = lane >> 5;
    int coff = hh * 64 + (lane & 31) * 2;
    bool havePrev = (c > 0);

    const float* aw0 = aw_g + ((size_t)b * NH + h2 * 2) * SEQ;
    for (int i = t; i < 1024; i += 512) {
        int hd = i >> 9, cc = (i >> 8) & 1, j = i & 255;
        float v = 0.f;
        if (cc == 1) v = aw0[hd * SEQ + c * WIN + j];
        else if (havePrev) v = aw0[hd * SEQ + (c - 1) * WIN + j];
        awl[hd][cc][j] = v;
    }
    __syncthreads();

    const u16* xb = x + (size_t)b * SEQ * xstride + h2 * 128 + coff;
    int jp0 = (havePrev ? c - 1 : c) * WIN;   // clamped when c==0 (aw=0 kills it)
    int jc0 = c * WIN;
    int j0 = wave * 32;

    // step A: per-wave sub-strip totals over rows [j0, j0+32) of both chunks
    float s0a = 0, s0b = 0, s1a = 0, s1b = 0, z0 = 0, z1 = 0;
    #pragma unroll 8
    for (int jj = 0; jj < 32; ++jj) {
        int j = j0 + jj;
        float ap = awl[hh][0][j], ac = awl[hh][1][j];
        unsigned up = *(const unsigned*)(xb + (size_t)(jp0 + j) * xstride);
        unsigned uc = *(const unsigned*)(xb + (size_t)(jc0 + j) * xstride);
        s0a += ap * bfu(up & 0xffff); s0b += ap * bfu(up >> 16); z0 += ap;
        s1a += ac * bfu(uc & 0xffff); s1b += ac * bfu(uc >> 16); z1 += ac;
    }
    sts[0][wave][lane] = make_float2(s0a, s0b);
    sts[1][wave][lane] = make_float2(s1a, s1b);
    if ((lane & 31) == 0) { stz[0][wave][hh] = z0; stz[1][wave][hh] = z1; }
    __syncthreads();

    // step B: carries + chunk-(c-1) totals
    float cs0a = 0, cs0b = 0, cs1a = 0, cs1b = 0, cz0 = 0, cz1 = 0;
    float totsa = 0, totsb = 0, totz = 0;
    #pragma unroll
    for (int w2 = 0; w2 < 8; ++w2) {
        float2 sp = sts[0][w2][lane];
        float zp = stz[0][w2][hh];
        totsa += sp.x; totsb += sp.y; totz += zp;
        if (w2 < wave) {
            cs0a += sp.x; cs0b += sp.y; cz0 += zp;
            float2 sc = sts[1][w2][lane];
            cs1a += sc.x; cs1b += sc.y; cz1 += stz[1][w2][hh];
        }
    }

    // step C: rescan with carries, emit
    float rpa = cs0a, rpb = cs0b, rca = cs1a, rcb = cs1b, rzp = cz0, rzc = cz1;
    size_t rowbase = (size_t)b * SEQ + jc0;
    #pragma unroll 4
    for (int jj = 0; jj < 32; ++jj) {
        int j = j0 + jj;
        float ap = awl[hh][0][j], ac = awl[hh][1][j];
        unsigned up = *(const unsigned*)(xb + (size_t)(jp0 + j) * xstride);
        unsigned uc = *(const unsigned*)(xb + (size_t)(jc0 + j) * xstride);
        rpa += ap * bfu(up & 0xffff); rpb += ap * bfu(up >> 16); rzp += ap;
        rca += ac * bfu(uc & 0xffff); rcb += ac * bfu(uc >> 16); rzc += ac;
        float inv = 1.f / (rzc + totz - rzp);
        float wva = (rca + totsa - rpa) * inv;
        float wvb = (rcb + totsb - rpb) * inv;
        if (fused) {
            size_t roff = (rowbase + j) * 3072 + h2 * 128 + coff;
            unsigned rr = *(const unsigned*)(resv + roff);
            unsigned vv = *(const unsigned*)(resv + roff + 2048);
            float2 o;
            o.x = bfu(rr & 0xffff) + wva * bfu(vv & 0xffff);
            o.y = bfu(rr >> 16)    + wvb * bfu(vv >> 16);
            *(float2*)(outF + (rowbase + j) * HID + h2 * 128 + coff) = o;
        } else {
            unsigned pk = (unsigned)f2bf(wva) | ((unsigned)f2bf(wvb) << 16);
            *(unsigned*)(out_bf + (rowbase + j) * HID + h2 * 128 + coff) = pk;
        }
    }
}

// ---------------------------------------------------------------- residual + LN2 + fused key-attn logits
__global__ __launch_bounds__(256) void resid_ln2(
    const u16* h, u16* qkv,
    const float* __restrict__ g, const float* __restrict__ b,
    const float* __restrict__ ka, const float* __restrict__ mask,
    u16* mixed, float* __restrict__ aw2)
{
    int row = blockIdx.x;
    int t = threadIdx.x;
    ushort4 h4 = ((const ushort4*)(h + (size_t)row * HID))[t];
    ushort4 p4 = ((const ushort4*)(qkv + (size_t)row * 3072))[t];
    ushort4 k4 = ((const ushort4*)(qkv + (size_t)row * 3072 + 1024))[t];
    float r0 = bfu(h4.x) + bfu(p4.x) * bfu(k4.x);
    float r1 = bfu(h4.y) + bfu(p4.y) * bfu(k4.y);
    float r2 = bfu(h4.z) + bfu(p4.z) * bfu(k4.z);
    float r3 = bfu(h4.w) + bfu(p4.w) * bfu(k4.w);
    ushort4 rb;
    rb.x = f2bf(r0); rb.y = f2bf(r1); rb.z = f2bf(r2); rb.w = f2bf(r3);
    ((ushort4*)(qkv + (size_t)row * 3072))[t] = rb;   // residual bf16 over dead pq

    float s  = r0 + r1 + r2 + r3;
    float ss = r0 * r0 + r1 * r1 + r2 * r2 + r3 * r3;
    __shared__ float red[8];
    #pragma unroll
    for (int off = 32; off; off >>= 1) { s += __shfl_down(s, off); ss += __shfl_down(ss, off); }
    int wave = t >> 6, lane = t & 63;
    if (lane == 0) { red[wave] = s; red[4 + wave] = ss; }
    __syncthreads();
    float S  = red[0] + red[1] + red[2] + red[3];
    float SS = red[4] + red[5] + red[6] + red[7];
    float mean = S * (1.f / HID);
    float var  = SS * (1.f / HID) - mean * mean;
    float inv  = rsqrtf(var + LN_EPS);
    float4 gv = ((const float4*)g)[t];
    float4 bv = ((const float4*)b)[t];
    float n0 = (r0 - mean) * inv * gv.x + bv.x;
    float n1 = (r1 - mean) * inv * gv.y + bv.y;
    float n2 = (r2 - mean) * inv * gv.z + bv.z;
    float n3 = (r3 - mean) * inv * gv.w + bv.w;
    ushort4 o;
    o.x = f2bf(n0); o.y = f2bf(n1); o.z = f2bf(n2); o.w = f2bf(n3);
    ((ushort4*)(mixed + (size_t)row * HID))[t] = o;

    // fused logits for second attention: head = t>>4
    float4 kv = ((const float4*)ka)[t];
    float partial = n0 * kv.x + n1 * kv.y + n2 * kv.z + n3 * kv.w;
    partial += __shfl_xor(partial, 1);
    partial += __shfl_xor(partial, 2);
    partial += __shfl_xor(partial, 4);
    partial += __shfl_xor(partial, 8);
    if ((t & 15) == 0) {
        int hh = t >> 4;
        int bb = row >> 12, sl = row & (SEQ - 1);
        float ma = (1.0f - mask[row]) * -10000.0f;
        aw2[((size_t)bb * NH + hh) * SEQ + sl] = expf(partial * 0.125f + ma);
    }
}

extern "C" void kernel_launch(void* const* d_in, const int* in_sizes, int n_in,
                              void* d_out, int out_size, void* d_ws, size_t ws_size,
                              hipStream_t stream)
{
    const float* hidden = (const float*)d_in[0];
    const float* mask   = (const float*)d_in[1];
    const float* Wq     = (const float*)d_in[2];
    const float* Wk     = (const float*)d_in[3];
    const float* Wv     = (const float*)d_in[4];
    const float* Wp     = (const float*)d_in[5];
    const float* qa     = (const float*)d_in[6];
    const float* ka     = (const float*)d_in[7];
    const float* g1     = (const float*)d_in[8];
    const float* b1     = (const float*)d_in[9];
    const float* g2     = (const float*)d_in[10];
    const float* b2     = (const float*)d_in[11];
    float* out = (float*)d_out;

    // workspace: 8 + 32 + 96 + 32 + 1 + 1 = 170 MB
    char* ws = (char*)d_ws;
    u16* wbf = (u16*)ws;       ws += (size_t)4 * 1024 * 1024 * 2;     //  8 MB  Wq|Wk|Wv|Wp bf16
    u16* hbf = (u16*)ws;       ws += (size_t)NROWS * HID * 2;         // 32 MB  h (later: mixed, in place)
    u16* qkv = (u16*)ws;       ws += (size_t)NROWS * 3072 * 2;        // 96 MB  q|k|v (q-cols: pq, then residual)
    u16* pooled = (u16*)ws;    ws += (size_t)NROWS * HID * 2;         // 32 MB  pooled_q
    float* aw1 = (float*)ws;   ws += (size_t)BATCH * NH * SEQ * 4;    //  1 MB
    float* aw2 = (float*)ws;                                          //  1 MB

    ln1_conv<<<NROWS + 4096, 256, 0, stream>>>(hidden, g1, b1, hbf, Wq, Wk, Wv, Wp, wbf);
    // qkv GEMM + fused attn1 logits: 8 xcd x 8 bmi x 24 bn = 1536 blocks
    gemm_bk32<<<1536, 512, 0, stream>>>(hbf, wbf, qkv, 3072, 24, qa, mask, aw1);
    attn_win2<<<dim3(SEQ / WIN, NH / 2, BATCH), 512, 0, stream>>>(
        qkv, 3072, aw1, pooled, (const u16*)nullptr, (float*)nullptr, 0);
    // pooled_q @ Wp.T -> qkv cols 0..1023 (q is dead): 8 x 8 x 8 = 512 blocks
    gemm_bk32<<<512, 512, 0, stream>>>(pooled, wbf + (size_t)3 * 1024 * 1024, qkv, 3072, 8,
                                       (const float*)nullptr, (const float*)nullptr, (float*)nullptr);
    resid_ln2<<<NROWS, 256, 0, stream>>>(hbf, qkv, g2, b2, ka, mask, hbf, aw2);
    // second attention fused with final: out = res + win * v
    attn_win2<<<dim3(SEQ / WIN, NH / 2, BATCH), 512, 0, stream>>>(
        hbf, HID, aw2, (u16*)nullptr, qkv, out, 1);
}

// Round 16
// 279.556 us; speedup vs baseline: 1.0528x; 1.0528x over previous
//
#include <hip/hip_runtime.h>
#include <hip/hip_bf16.h>

#define HID 1024
#define NH 16
#define HEAD 64
#define WIN 256
#define SEQ 4096
#define BATCH 4
#define NROWS (BATCH * SEQ)   // 16384
#define LN_EPS 1e-5f

typedef unsigned short u16;
typedef __bf16 bf16x8 __attribute__((ext_vector_type(8)));
typedef float f32x4 __attribute__((ext_vector_type(4)));

static __device__ inline float bfu(u16 u) {
    union { unsigned int i; float f; } x;
    x.i = ((unsigned int)u) << 16;
    return x.f;
}

static __device__ inline u16 f2bf(float f) {
    union { float f; unsigned int i; } x;
    x.f = f;
    unsigned int lsb = (x.i >> 16) & 1u;
    x.i += 0x7fffu + lsb;   // round-to-nearest-even
    return (u16)(x.i >> 16);
}

// ---------------------------------------------------------------- fused LN1 + weight convert
__global__ __launch_bounds__(256) void ln1_conv(
    const float* __restrict__ x, const float* __restrict__ g,
    const float* __restrict__ b, u16* __restrict__ out,
    const float* __restrict__ wq, const float* __restrict__ wk,
    const float* __restrict__ wv, const float* __restrict__ wp,
    u16* __restrict__ wo)
{
    __shared__ float red[8];
    int t = threadIdx.x;
    if (blockIdx.x >= NROWS) {
        int i = (blockIdx.x - NROWS) * 256 + t;
        const int n = 1024 * 1024;
        wo[i]         = f2bf(wq[i]);
        wo[n + i]     = f2bf(wk[i]);
        wo[2 * n + i] = f2bf(wv[i]);
        wo[3 * n + i] = f2bf(wp[i]);
        return;
    }
    int row = blockIdx.x;
    float4 v = ((const float4*)(x + (size_t)row * HID))[t];
    float s  = v.x + v.y + v.z + v.w;
    float ss = v.x * v.x + v.y * v.y + v.z * v.z + v.w * v.w;
    #pragma unroll
    for (int off = 32; off; off >>= 1) { s += __shfl_down(s, off); ss += __shfl_down(ss, off); }
    int wave = t >> 6, lane = t & 63;
    if (lane == 0) { red[wave] = s; red[4 + wave] = ss; }
    __syncthreads();
    float S  = red[0] + red[1] + red[2] + red[3];
    float SS = red[4] + red[5] + red[6] + red[7];
    float mean = S * (1.f / HID);
    float var  = SS * (1.f / HID) - mean * mean;
    float inv  = rsqrtf(var + LN_EPS);
    float4 gv = ((const float4*)g)[t];
    float4 bv = ((const float4*)b)[t];
    ushort4 o;
    o.x = f2bf((v.x - mean) * inv * gv.x + bv.x);
    o.y = f2bf((v.y - mean) * inv * gv.y + bv.y);
    o.z = f2bf((v.z - mean) * inv * gv.z + bv.z);
    o.w = f2bf((v.w - mean) * inv * gv.w + bv.w);
    ((ushort4*)(out + (size_t)row * HID))[t] = o;
}

// ---------------------------------------------------------------- 256x128 BK=32 triple-buffered GEMM
// K=1024 (nk=32). Wave grid 4M x 2N, per-wave 64x64 (acc 64 VGPR).
// LDS 3x24KB = 72KB -> 2 blocks/CU. Swizzle f(r)=(r>>1)&3 (0-conflict).
// bm-FAST XCD decode (round-16 revert: bn-fast thrashed L2 -> FETCH 86->163MB;
// keep the small 256KB B-panel hot per stripe, A 4MB sweep borderline-resident).
// Fused attn1-logits epilogue for bn<8 blocks (wave wc owns head bn*2+wc).
#define GLDS(gp, lp) __builtin_amdgcn_global_load_lds( \
    (const __attribute__((address_space(1))) void*)(gp), \
    (__attribute__((address_space(3))) void*)(lp), 16, 0, 0)

__global__ __launch_bounds__(512, 4) void gemm_bk32(
    const u16* __restrict__ A, const u16* __restrict__ W,
    u16* __restrict__ C, int ldc,
    const float* __restrict__ qa,     // if non-null: fused logits for bn<8 tiles
    const float* __restrict__ mask,
    float* __restrict__ awout)
{
    // per buf (u16 units): A-unit0 [0,4096), A-unit1 [4096,8192), B [8192,12288)
    // A unit0 holds rows 0-63 & 128-191; unit1 rows 64-127 & 192-255.
    __shared__ __align__(16) u16 lds[3][12288];   // 72 KB

    const int tid = threadIdx.x;
    const int wave = tid >> 6, lane = tid & 63;
    const int wr = wave >> 1, wc = wave & 1;           // 4M x 2N
    const int li = lane & 15;
    const int kg = lane >> 4;                          // K-group 0..3
    const int swz = (kg * 8) ^ (((li >> 1) & 3) << 3); // swizzled elem-in-row

    // bm-fast XCD decode (R14): xcd = bid&7 owns bm stripe [xcd*8, xcd*8+8)
    const int bm = (blockIdx.x & 7) * 8 + ((blockIdx.x >> 3) & 7);
    const int bn = blockIdx.x >> 6;

    // staging: thread covers 16B of row rp (0..127) in each 8KB unit;
    // source col pre-swizzled with the SAME f(r)=(r>>1)&3 involution.
    const int rp = tid >> 2;
    const int colE = (((tid & 3) * 16) ^ (((rp >> 1) & 3) << 4)) >> 1;  // elem col 0..31
    const int rowA0 = rp + (rp >= 64 ? 64 : 0);   // unit0: rows 0-63 & 128-191
    const u16* gA0 = A + (size_t)(bm * 256 + rowA0) * 1024 + colE;
    const u16* gA1 = gA0 + (size_t)64 * 1024;     // unit1: rows 64-127 & 192-255
    const u16* gB  = W + (size_t)(bn * 128 + rp) * 1024 + colE;

    // per-wave A source: unit (wr&1), base row (wr>>1)*64
    const int aUnit = (wr & 1) * 4096;
    const int aRow0 = (wr >> 1) * 64;

    // prologue: stage tiles 0,1 into bufs 0,1; drain tile 0.
    #pragma unroll
    for (int t = 0; t < 2; ++t) {
        u16* d = &lds[t][0];
        GLDS(gA0 + t * 32, d + tid * 8);
        GLDS(gA1 + t * 32, d + 4096 + tid * 8);
        GLDS(gB  + t * 32, d + 8192 + tid * 8);
    }
    asm volatile("s_waitcnt vmcnt(3)" ::: "memory");
    __builtin_amdgcn_sched_barrier(0);
    __builtin_amdgcn_s_barrier();
    __builtin_amdgcn_sched_barrier(0);

    f32x4 acc[4][4];
    #pragma unroll
    for (int m = 0; m < 4; ++m)
        #pragma unroll
        for (int n = 0; n < 4; ++n) {
            f32x4 z = {0.f, 0.f, 0.f, 0.f};
            acc[m][n] = z;
        }

    const u16* rb = &lds[0][0];
    const u16* rn = &lds[1][0];
    u16* wb = &lds[2][0];

    for (int kt = 0; kt < 32; ++kt) {
        // reads at top (tile kt's buf was drained at iter kt-1's wait)
        bf16x8 bF[4], aF01[2];
        #pragma unroll
        for (int n = 0; n < 4; ++n)
            bF[n] = *(const bf16x8*)&rb[8192 + (wc * 64 + n * 16 + li) * 32 + swz];
        #pragma unroll
        for (int i = 0; i < 2; ++i)
            aF01[i] = *(const bf16x8*)&rb[aUnit + (aRow0 + i * 16 + li) * 32 + swz];

        // stage tile kt+2 into wb (last read as rb at iter kt-1)
        if (kt < 30) {
            const int ko = (kt + 2) * 32;
            GLDS(gA0 + ko, wb + tid * 8);
            GLDS(gA1 + ko, wb + 4096 + tid * 8);
            GLDS(gB  + ko, wb + 8192 + tid * 8);
        }
        // wait: drain tile kt+1's 3 units (staged at iter kt-1, ~1 K-tile old)
        if (kt < 31) {
            if (kt < 30) asm volatile("s_waitcnt vmcnt(3)" ::: "memory");
            else         asm volatile("s_waitcnt vmcnt(0)" ::: "memory");
        }
        __builtin_amdgcn_sched_barrier(0);
        __builtin_amdgcn_s_barrier();
        __builtin_amdgcn_sched_barrier(0);

        __builtin_amdgcn_s_setprio(1);
        #pragma unroll
        for (int i = 0; i < 2; ++i)
            #pragma unroll
            for (int n = 0; n < 4; ++n)
                acc[i][n] = __builtin_amdgcn_mfma_f32_16x16x32_bf16(
                    aF01[i], bF[n], acc[i][n], 0, 0, 0);
        bf16x8 aF23[2];
        #pragma unroll
        for (int i = 0; i < 2; ++i)
            aF23[i] = *(const bf16x8*)&rb[aUnit + (aRow0 + (i + 2) * 16 + li) * 32 + swz];
        #pragma unroll
        for (int i = 0; i < 2; ++i)
            #pragma unroll
            for (int n = 0; n < 4; ++n)
                acc[2 + i][n] = __builtin_amdgcn_mfma_f32_16x16x32_bf16(
                    aF23[i], bF[n], acc[2 + i][n], 0, 0, 0);
        __builtin_amdgcn_s_setprio(0);
        __builtin_amdgcn_sched_barrier(0);
        __builtin_amdgcn_s_barrier();
        __builtin_amdgcn_sched_barrier(0);

        const u16* tmp = rb; rb = rn; rn = wb; wb = (u16*)tmp;
    }

    // fused attn1 logits: q cols are 0..1023 -> bn<8; wave wc owns head bn*2+wc.
    // Output row lives in the 16-lane kg-group matching its kg*4+r.
    if (awout != nullptr && bn < 8) {
        float qav[4];
        #pragma unroll
        for (int n = 0; n < 4; ++n)
            qav[n] = qa[bn * 128 + wc * 64 + n * 16 + li];
        #pragma unroll
        for (int mf = 0; mf < 4; ++mf) {
            #pragma unroll
            for (int r = 0; r < 4; ++r) {
                float d = acc[mf][0][r] * qav[0] + acc[mf][1][r] * qav[1]
                        + acc[mf][2][r] * qav[2] + acc[mf][3][r] * qav[3];
                d += __shfl_xor(d, 1);
                d += __shfl_xor(d, 2);
                d += __shfl_xor(d, 4);
                d += __shfl_xor(d, 8);
                if (li == 0) {
                    int row = bm * 256 + wr * 64 + mf * 16 + kg * 4 + r;
                    float ma = (1.0f - mask[row]) * -10000.0f;
                    awout[(((size_t)(row >> 12)) * NH + bn * 2 + wc) * SEQ + (row & (SEQ - 1))] =
                        expf(d * 0.125f + ma);
                }
            }
        }
    }

    #pragma unroll
    for (int mf = 0; mf < 4; ++mf) {
        int row0 = bm * 256 + wr * 64 + mf * 16 + kg * 4;
        #pragma unroll
        for (int n = 0; n < 4; ++n) {
            int col = bn * 128 + wc * 64 + n * 16 + li;
            #pragma unroll
            for (int r = 0; r < 4; ++r)
                C[(size_t)(row0 + r) * ldc + col] = f2bf(acc[mf][n][r]);
        }
    }
}

// ---------------------------------------------------------------- windowed scan attention, 2 heads/block
// fused==0: out_bf <- windowed avg (bf16). fused==1: outF <- res + win*v (write-only).
__global__ __launch_bounds__(512) void attn_win2(
    const u16* __restrict__ x, int xstride,
    const float* __restrict__ aw_g,
    u16* __restrict__ out_bf,
    const u16* __restrict__ resv,   // qkv base: res in cols 0..1023, v in cols 2048..3071
    float* __restrict__ outF,
    int fused)
{
    int c = blockIdx.x, h2 = blockIdx.y, b = blockIdx.z;
    __shared__ float awl[2][2][WIN];     // [head][chunk][j]
    __shared__ float2 sts[2][8][64];     // [chunk][wave][lane]
    __shared__ float stz[2][8][2];       // [chunk][wave][head]

    int t = threadIdx.x, wave = t >> 6, lane = t & 63;
    int hh = lane >> 5;
    int coff = hh * 64 + (lane & 31) * 2;
    bool havePrev = (c > 0);

    const float* aw0 = aw_g + ((size_t)b * NH + h2 * 2) * SEQ;
    for (int i = t; i < 1024; i += 512) {
        int hd = i >> 9, cc = (i >> 8) & 1, j = i & 255;
        float v = 0.f;
        if (cc == 1) v = aw0[hd * SEQ + c * WIN + j];
        else if (havePrev) v = aw0[hd * SEQ + (c - 1) * WIN + j];
        awl[hd][cc][j] = v;
    }
    __syncthreads();

    const u16* xb = x + (size_t)b * SEQ * xstride + h2 * 128 + coff;
    int jp0 = (havePrev ? c - 1 : c) * WIN;   // clamped when c==0 (aw=0 kills it)
    int jc0 = c * WIN;
    int j0 = wave * 32;

    // step A: per-wave sub-strip totals over rows [j0, j0+32) of both chunks
    float s0a = 0, s0b = 0, s1a = 0, s1b = 0, z0 = 0, z1 = 0;
    #pragma unroll 8
    for (int jj = 0; jj < 32; ++jj) {
        int j = j0 + jj;
        float ap = awl[hh][0][j], ac = awl[hh][1][j];
        unsigned up = *(const unsigned*)(xb + (size_t)(jp0 + j) * xstride);
        unsigned uc = *(const unsigned*)(xb + (size_t)(jc0 + j) * xstride);
        s0a += ap * bfu(up & 0xffff); s0b += ap * bfu(up >> 16); z0 += ap;
        s1a += ac * bfu(uc & 0xffff); s1b += ac * bfu(uc >> 16); z1 += ac;
    }
    sts[0][wave][lane] = make_float2(s0a, s0b);
    sts[1][wave][lane] = make_float2(s1a, s1b);
    if ((lane & 31) == 0) { stz[0][wave][hh] = z0; stz[1][wave][hh] = z1; }
    __syncthreads();

    // step B: carries + chunk-(c-1) totals
    float cs0a = 0, cs0b = 0, cs1a = 0, cs1b = 0, cz0 = 0, cz1 = 0;
    float totsa = 0, totsb = 0, totz = 0;
    #pragma unroll
    for (int w2 = 0; w2 < 8; ++w2) {
        float2 sp = sts[0][w2][lane];
        float zp = stz[0][w2][hh];
        totsa += sp.x; totsb += sp.y; totz += zp;
        if (w2 < wave) {
            cs0a += sp.x; cs0b += sp.y; cz0 += zp;
            float2 sc = sts[1][w2][lane];
            cs1a += sc.x; cs1b += sc.y; cz1 += stz[1][w2][hh];
        }
    }

    // step C: rescan with carries, emit
    float rpa = cs0a, rpb = cs0b, rca = cs1a, rcb = cs1b, rzp = cz0, rzc = cz1;
    size_t rowbase = (size_t)b * SEQ + jc0;
    #pragma unroll 4
    for (int jj = 0; jj < 32; ++jj) {
        int j = j0 + jj;
        float ap = awl[hh][0][j], ac = awl[hh][1][j];
        unsigned up = *(const unsigned*)(xb + (size_t)(jp0 + j) * xstride);
        unsigned uc = *(const unsigned*)(xb + (size_t)(jc0 + j) * xstride);
        rpa += ap * bfu(up & 0xffff); rpb += ap * bfu(up >> 16); rzp += ap;
        rca += ac * bfu(uc & 0xffff); rcb += ac * bfu(uc >> 16); rzc += ac;
        float inv = 1.f / (rzc + totz - rzp);
        float wva = (rca + totsa - rpa) * inv;
        float wvb = (rcb + totsb - rpb) * inv;
        if (fused) {
            size_t roff = (rowbase + j) * 3072 + h2 * 128 + coff;
            unsigned rr = *(const unsigned*)(resv + roff);
            unsigned vv = *(const unsigned*)(resv + roff + 2048);
            float2 o;
            o.x = bfu(rr & 0xffff) + wva * bfu(vv & 0xffff);
            o.y = bfu(rr >> 16)    + wvb * bfu(vv >> 16);
            *(float2*)(outF + (rowbase + j) * HID + h2 * 128 + coff) = o;
        } else {
            unsigned pk = (unsigned)f2bf(wva) | ((unsigned)f2bf(wvb) << 16);
            *(unsigned*)(out_bf + (rowbase + j) * HID + h2 * 128 + coff) = pk;
        }
    }
}

// ---------------------------------------------------------------- residual + LN2 + fused key-attn logits
__global__ __launch_bounds__(256) void resid_ln2(
    const u16* h, u16* qkv,
    const float* __restrict__ g, const float* __restrict__ b,
    const float* __restrict__ ka, const float* __restrict__ mask,
    u16* mixed, float* __restrict__ aw2)
{
    int row = blockIdx.x;
    int t = threadIdx.x;
    ushort4 h4 = ((const ushort4*)(h + (size_t)row * HID))[t];
    ushort4 p4 = ((const ushort4*)(qkv + (size_t)row * 3072))[t];
    ushort4 k4 = ((const ushort4*)(qkv + (size_t)row * 3072 + 1024))[t];
    float r0 = bfu(h4.x) + bfu(p4.x) * bfu(k4.x);
    float r1 = bfu(h4.y) + bfu(p4.y) * bfu(k4.y);
    float r2 = bfu(h4.z) + bfu(p4.z) * bfu(k4.z);
    float r3 = bfu(h4.w) + bfu(p4.w) * bfu(k4.w);
    ushort4 rb;
    rb.x = f2bf(r0); rb.y = f2bf(r1); rb.z = f2bf(r2); rb.w = f2bf(r3);
    ((ushort4*)(qkv + (size_t)row * 3072))[t] = rb;   // residual bf16 over dead pq

    float s  = r0 + r1 + r2 + r3;
    float ss = r0 * r0 + r1 * r1 + r2 * r2 + r3 * r3;
    __shared__ float red[8];
    #pragma unroll
    for (int off = 32; off; off >>= 1) { s += __shfl_down(s, off); ss += __shfl_down(ss, off); }
    int wave = t >> 6, lane = t & 63;
    if (lane == 0) { red[wave] = s; red[4 + wave] = ss; }
    __syncthreads();
    float S  = red[0] + red[1] + red[2] + red[3];
    float SS = red[4] + red[5] + red[6] + red[7];
    float mean = S * (1.f / HID);
    float var  = SS * (1.f / HID) - mean * mean;
    float inv  = rsqrtf(var + LN_EPS);
    float4 gv = ((const float4*)g)[t];
    float4 bv = ((const float4*)b)[t];
    float n0 = (r0 - mean) * inv * gv.x + bv.x;
    float n1 = (r1 - mean) * inv * gv.y + bv.y;
    float n2 = (r2 - mean) * inv * gv.z + bv.z;
    float n3 = (r3 - mean) * inv * gv.w + bv.w;
    ushort4 o;
    o.x = f2bf(n0); o.y = f2bf(n1); o.z = f2bf(n2); o.w = f2bf(n3);
    ((ushort4*)(mixed + (size_t)row * HID))[t] = o;

    // fused logits for second attention: head = t>>4
    float4 kv = ((const float4*)ka)[t];
    float partial = n0 * kv.x + n1 * kv.y + n2 * kv.z + n3 * kv.w;
    partial += __shfl_xor(partial, 1);
    partial += __shfl_xor(partial, 2);
    partial += __shfl_xor(partial, 4);
    partial += __shfl_xor(partial, 8);
    if ((t & 15) == 0) {
        int hh = t >> 4;
        int bb = row >> 12, sl = row & (SEQ - 1);
        float ma = (1.0f - mask[row]) * -10000.0f;
        aw2[((size_t)bb * NH + hh) * SEQ + sl] = expf(partial * 0.125f + ma);
    }
}

extern "C" void kernel_launch(void* const* d_in, const int* in_sizes, int n_in,
                              void* d_out, int out_size, void* d_ws, size_t ws_size,
                              hipStream_t stream)
{
    const float* hidden = (const float*)d_in[0];
    const float* mask   = (const float*)d_in[1];
    const float* Wq     = (const float*)d_in[2];
    const float* Wk     = (const float*)d_in[3];
    const float* Wv     = (const float*)d_in[4];
    const float* Wp     = (const float*)d_in[5];
    const float* qa     = (const float*)d_in[6];
    const float* ka     = (const float*)d_in[7];
    const float* g1     = (const float*)d_in[8];
    const float* b1     = (const float*)d_in[9];
    const float* g2     = (const float*)d_in[10];
    const float* b2     = (const float*)d_in[11];
    float* out = (float*)d_out;

    // workspace: 8 + 32 + 96 + 32 + 1 + 1 = 170 MB
    char* ws = (char*)d_ws;
    u16* wbf = (u16*)ws;       ws += (size_t)4 * 1024 * 1024 * 2;     //  8 MB  Wq|Wk|Wv|Wp bf16
    u16* hbf = (u16*)ws;       ws += (size_t)NROWS * HID * 2;         // 32 MB  h (later: mixed, in place)
    u16* qkv = (u16*)ws;       ws += (size_t)NROWS * 3072 * 2;        // 96 MB  q|k|v (q-cols: pq, then residual)
    u16* pooled = (u16*)ws;    ws += (size_t)NROWS * HID * 2;         // 32 MB  pooled_q
    float* aw1 = (float*)ws;   ws += (size_t)BATCH * NH * SEQ * 4;    //  1 MB
    float* aw2 = (float*)ws;                                          //  1 MB

    ln1_conv<<<NROWS + 4096, 256, 0, stream>>>(hidden, g1, b1, hbf, Wq, Wk, Wv, Wp, wbf);
    // qkv GEMM + fused attn1 logits: 1536 blocks (bm-fast stripes, bn = bid>>6)
    gemm_bk32<<<1536, 512, 0, stream>>>(hbf, wbf, qkv, 3072, qa, mask, aw1);
    attn_win2<<<dim3(SEQ / WIN, NH / 2, BATCH), 512, 0, stream>>>(
        qkv, 3072, aw1, pooled, (const u16*)nullptr, (float*)nullptr, 0);
    // pooled_q @ Wp.T -> qkv cols 0..1023 (q is dead): 512 blocks
    gemm_bk32<<<512, 512, 0, stream>>>(pooled, wbf + (size_t)3 * 1024 * 1024, qkv, 3072,
                                       (const float*)nullptr, (const float*)nullptr, (float*)nullptr);
    resid_ln2<<<NROWS, 256, 0, stream>>>(hbf, qkv, g2, b2, ka, mask, hbf, aw2);
    // second attention fused with final: out = res + win * v
    attn_win2<<<dim3(SEQ / WIN, NH / 2, BATCH), 512, 0, stream>>>(
        hbf, HID, aw2, (u16*)nullptr, qkv, out, 1);
}